// Round 2
// baseline (498.793 us; speedup 1.0000x reference)
//
#include <hip/hip_runtime.h>

typedef __bf16 bf16x8 __attribute__((ext_vector_type(8)));
typedef __bf16 bf16x2 __attribute__((ext_vector_type(2)));
typedef float  f32x4  __attribute__((ext_vector_type(4)));

// sizes: E=4 B=32 CI=64 H=W=64 CO=128 OH=OW=62
// ws layout: [0, 64MiB) features bf16 NHWC [eb][y][x][i]
//            [64MiB, +576KiB) weights bf16 [e][tap][j][i]
#define FT_BYTES 67108864ull

__device__ __forceinline__ void gl2lds16(const void* g, void* l) {
    __builtin_amdgcn_global_load_lds(
        (const __attribute__((address_space(1))) void*)g,
        (__attribute__((address_space(3))) void*)l, 16, 0, 0);
}

// prepass 1: weight fp32 [e][i][j][tap] -> bf16 [e][tap][j][i]
__global__ void wt_prep(const float* __restrict__ w, __bf16* __restrict__ wt) {
    int o = blockIdx.x * 256 + threadIdx.x;           // 294912 total
    int i = o & 63, j = (o >> 6) & 127, et = o >> 13; // et 0..35
    int tap = et % 9, e = et / 9;
    wt[o] = (__bf16)w[((e * 64 + i) * 128 + j) * 9 + tap];
}

// prepass 2: features fp32 NCHW -> bf16 NHWC, one block per (e,b,y)
__global__ void ft_prep(const float* __restrict__ f, __bf16* __restrict__ ft) {
    __shared__ float s[64 * 65];                      // [i][x], +1 pad
    int eb = blockIdx.z * 32 + blockIdx.y, y = blockIdx.x;
    const float* src = f + (size_t)eb * 262144 + y * 64;
    int t = threadIdx.x;
    for (int r = 0; r < 4; ++r) {
        int f4 = r * 256 + t;                         // 1024 float4
        int i = f4 >> 4, x4 = (f4 & 15) * 4;
        float4 v = *(const float4*)(src + i * 4096 + x4);
        s[i * 65 + x4 + 0] = v.x; s[i * 65 + x4 + 1] = v.y;
        s[i * 65 + x4 + 2] = v.z; s[i * 65 + x4 + 3] = v.w;
    }
    __syncthreads();
    bf16x2* dst = (bf16x2*)(ft + (size_t)(eb * 64 + y) * 4096);
    for (int r = 0; r < 8; ++r) {
        int q = r * 256 + t;                          // 2048 bf16x2; q = x*32+ih
        int x = q >> 5, ih = q & 31;
        bf16x2 pv;
        pv.x = (__bf16)s[(2 * ih + 0) * 65 + x];
        pv.y = (__bf16)s[(2 * ih + 1) * 65 + x];
        dst[q] = pv;
    }
}

// main: per block (e,b,2-row group): out tile 128(j) x 128(p=2y*64x)
// Barrier-free K-loop:
//  - sF: ALL feature rows the block needs (y0..y0+3, 256 R-rows x 64i, 32KB)
//    staged ONCE via global_load_lds; every tap's (A,Bt) shift is applied at
//    LDS-read time (xx clamped; overflow feeds only dead px>=62 columns).
//  - Weights: global->register, 8 x bf16x8 per wave per tap, double-buffered
//    across taps (weights are L2-resident; no LDS, no barrier).
//  - Exactly ONE __syncthreads per block; waves run free pipelines after it.
__global__ __launch_bounds__(256, 2)
void conv_main(const __bf16* __restrict__ ft, const __bf16* __restrict__ wt,
               const float* __restrict__ bias, float* __restrict__ out) {
    __shared__ __align__(16) __bf16 sF[256 * 64];     // [R=y*64+x][i] 32KB
    const int e = blockIdx.z, b = blockIdx.y, y0 = blockIdx.x * 2;
    const int eb = e * 32 + b;
    const int t = threadIdx.x, lane = t & 63, w = t >> 6;
    const int wm = w >> 1, wn = w & 1;                // 2x2 waves over (M,N)
    const int q = lane >> 4, rm = lane & 15;

    f32x4 acc[4][4] = {};
    // feature base at row (y0*64 + 0): [eb]*4096 rows, each 64 bf16
    const __bf16* ftb = ft + (size_t)eb * 262144 + ((size_t)y0 << 12);
    // per-lane weight pointer: + tap<<13 + mi*1024 + kh*32 later
    const __bf16* wbase = wt + ((size_t)(e * 9) << 13)
                        + (wm * 64 + rm) * 64 + q * 8;

    // stage sF once: 32 segments of 1KB; 16B chunk g stored at slot g^(r&7)
    for (int cc = 0; cc < 8; ++cc) {
        int c = w * 8 + cc;
        int r = c * 8 + (lane >> 3);                  // R-row 0..255
        int g = (lane & 7) ^ (r & 7);
        gl2lds16(ftb + (r << 6) + g * 8, sF + c * 512);
    }

    bf16x8 afA[8], afB[8];                            // [mi*2+kh]
    #pragma unroll
    for (int mi = 0; mi < 4; ++mi)
        #pragma unroll
        for (int kh = 0; kh < 2; ++kh)
            afA[mi * 2 + kh] = *(const bf16x8*)(wbase + mi * 1024 + kh * 32);

    __syncthreads();                                  // sF + tap0 weights ready

    auto body = [&](int tap, bf16x8* cur, bf16x8* nxt) {
        if (tap < 8) {                                // prefetch tap+1 weights
            const __bf16* wp = wbase + ((size_t)(tap + 1) << 13);
            #pragma unroll
            for (int mi = 0; mi < 4; ++mi)
                #pragma unroll
                for (int kh = 0; kh < 2; ++kh)
                    nxt[mi * 2 + kh] = *(const bf16x8*)(wp + mi * 1024 + kh * 32);
        }
        const int A = tap / 3, Bt = tap - A * 3;
        #pragma unroll
        for (int kh = 0; kh < 2; ++kh) {
            const int kg = kh * 4;
            bf16x8 bq[4];
            #pragma unroll
            for (int ni = 0; ni < 4; ++ni) {
                int p = wn * 64 + ni * 16 + rm;
                int py = p >> 6, px = p & 63;
                int xx = px + Bt; if (xx > 63) xx = 63;   // dead cols only
                int r2 = (A + py) * 64 + xx;
                int ch = (kg + q) ^ (r2 & 7);
                bq[ni] = *(const bf16x8*)(sF + r2 * 64 + ch * 8);
            }
            #pragma unroll
            for (int mi = 0; mi < 4; ++mi)
                #pragma unroll
                for (int ni = 0; ni < 4; ++ni)
                    acc[mi][ni] = __builtin_amdgcn_mfma_f32_16x16x32_bf16(
                        cur[mi * 2 + kh], bq[ni], acc[mi][ni], 0, 0, 0);
        }
    };

    #pragma unroll 1
    for (int tt = 0; tt < 4; ++tt) {                  // ping-pong, static idx
        body(2 * tt,     afA, afB);
        body(2 * tt + 1, afB, afA);
    }
    body(8, afA, afB);                                // tail (no prefetch)

    // epilogue: D layout col(n=p)=lane&15, row(m=j)=(lane>>4)*4+reg
    for (int mi = 0; mi < 4; ++mi) {
        for (int ni = 0; ni < 4; ++ni) {
            int p = wn * 64 + ni * 16 + rm;
            int py = p >> 6, px = p & 63;
            if (px >= 62) continue;                   // dead padding columns
            for (int vv = 0; vv < 4; ++vv) {
                int j = wm * 64 + mi * 16 + q * 4 + vv;
                float v = acc[mi][ni][vv] + bias[e * 128 + j];
                out[(((size_t)eb * 128 + j) * 62 + (y0 + py)) * 62 + px] = v;
            }
        }
    }
}

extern "C" void kernel_launch(void* const* d_in, const int* in_sizes, int n_in,
                              void* d_out, int out_size, void* d_ws, size_t ws_size,
                              hipStream_t stream) {
    const float* f    = (const float*)d_in[0];
    const float* wgt  = (const float*)d_in[1];
    const float* bias = (const float*)d_in[2];
    float* out = (float*)d_out;
    __bf16* ftw = (__bf16*)d_ws;
    __bf16* wtw = (__bf16*)((char*)d_ws + FT_BYTES);

    ft_prep<<<dim3(64, 32, 4), 256, 0, stream>>>(f, ftw);
    wt_prep<<<dim3(1152), 256, 0, stream>>>(wgt, wtw);
    conv_main<<<dim3(31, 32, 4), 256, 0, stream>>>(ftw, wtw, bias, out);
}

// Round 3
// 424.137 us; speedup vs baseline: 1.1760x; 1.1760x over previous
//
#include <hip/hip_runtime.h>

typedef __bf16 bf16x8 __attribute__((ext_vector_type(8)));
typedef __bf16 bf16x2 __attribute__((ext_vector_type(2)));
typedef float  f32x4  __attribute__((ext_vector_type(4)));

// sizes: E=4 B=32 CI=64 H=W=64 CO=128 OH=OW=62
// ws layout: [0, 64MiB) features bf16 NHWC [eb][y][x][i]
//            [64MiB, +576KiB) weights bf16 [e][tap][j][i]
#define FT_BYTES 67108864ull

__device__ __forceinline__ void gl2lds16(const void* g, void* l) {
    __builtin_amdgcn_global_load_lds(
        (const __attribute__((address_space(1))) void*)g,
        (__attribute__((address_space(3))) void*)l, 16, 0, 0);
}

// prepass 1: weight fp32 [e][i][j][tap] -> bf16 [e][tap][j][i]
__global__ void wt_prep(const float* __restrict__ w, __bf16* __restrict__ wt) {
    int o = blockIdx.x * 256 + threadIdx.x;           // 294912 total
    int i = o & 63, j = (o >> 6) & 127, et = o >> 13; // et 0..35
    int tap = et % 9, e = et / 9;
    wt[o] = (__bf16)w[((e * 64 + i) * 128 + j) * 9 + tap];
}

// prepass 2: features fp32 NCHW -> bf16 NHWC, one block per (e,b,y)
__global__ void ft_prep(const float* __restrict__ f, __bf16* __restrict__ ft) {
    __shared__ float s[64 * 65];                      // [i][x], +1 pad
    int eb = blockIdx.z * 32 + blockIdx.y, y = blockIdx.x;
    const float* src = f + (size_t)eb * 262144 + y * 64;
    int t = threadIdx.x;
    for (int r = 0; r < 4; ++r) {
        int f4 = r * 256 + t;                         // 1024 float4
        int i = f4 >> 4, x4 = (f4 & 15) * 4;
        float4 v = *(const float4*)(src + i * 4096 + x4);
        s[i * 65 + x4 + 0] = v.x; s[i * 65 + x4 + 1] = v.y;
        s[i * 65 + x4 + 2] = v.z; s[i * 65 + x4 + 3] = v.w;
    }
    __syncthreads();
    bf16x2* dst = (bf16x2*)(ft + (size_t)(eb * 64 + y) * 4096);
    for (int r = 0; r < 8; ++r) {
        int q = r * 256 + t;                          // 2048 bf16x2; q = x*32+ih
        int x = q >> 5, ih = q & 31;
        bf16x2 pv;
        pv.x = (__bf16)s[(2 * ih + 0) * 65 + x];
        pv.y = (__bf16)s[(2 * ih + 1) * 65 + x];
        dst[q] = pv;
    }
}

// main: block = (y-pair, j-half, e, b-group). 512 threads = 8 waves (2Mx4N).
// Streams 16 consecutive b images with weights LDS-resident:
//  - sW: all 9 taps of this j-half's weights (9 x 64j x 64i = 72KB), staged
//    ONCE per block via global_load_lds, reused for all 16 b-iterations.
//  - sF: 4 feature rows (y0..y0+3) of current b, 32KB, DOUBLE-buffered;
//    iter n+1's stage is issued before iter n's compute -> its vmcnt drain
//    at the single per-iter barrier is ~2000cy deep (hidden).
//  - All 9 (A,Bt) tap shifts applied at LDS-read time (clamped overflow
//    feeds only dead px>=62 columns).
//  - 1 barrier per b-iter; weight loads never appear in the main loop.
__global__ __launch_bounds__(512, 2)
void conv_main(const __bf16* __restrict__ ft, const __bf16* __restrict__ wt,
               const float* __restrict__ bias, float* __restrict__ out) {
    __shared__ __align__(16) __bf16 sW[9 * 4096];     // [tap][jl][i] 72KB
    __shared__ __align__(16) __bf16 sF[2][16384];     // [R=y*64+x][i] 2x32KB
    const int y0 = blockIdx.x * 2, jh = blockIdx.y;
    const int e = blockIdx.z >> 1, bg = blockIdx.z & 1;
    const int t = threadIdx.x, lane = t & 63, w = t >> 6;
    const int wm = w >> 2, wn = w & 3;                // 2x4 waves over (M=64,N=128)
    const int q = lane >> 4, rm = lane & 15;

    // stage sW: 72 wave-chunks of 1KB; 16B chunk g stored at slot g^(r&7)
    const __bf16* wte = wt + ((size_t)(e * 9) << 13) + (jh << 12);
    for (int k = 0; k < 9; ++k) {
        int s = w * 9 + k;                            // 0..71
        int tap = s >> 3;
        int r = (s & 7) * 8 + (lane >> 3);            // jl row 0..63
        int g = (lane & 7) ^ (r & 7);
        gl2lds16(wte + (tap << 13) + r * 64 + g * 8, sW + s * 512);
    }
    // stage sF[0] for it=0
    const __bf16* fte = ft + ((size_t)(e * 32 + bg * 16) << 18) + ((size_t)y0 << 12);
    for (int cc = 0; cc < 4; ++cc) {
        int c = w * 4 + cc;                           // 0..31
        int r = c * 8 + (lane >> 3);                  // R-row 0..255
        int g = (lane & 7) ^ (r & 7);
        gl2lds16(fte + (r << 6) + g * 8, sF[0] + c * 512);
    }

    // hoist bias for this wave's 8 j values
    float bias_r[2][4];
    for (int mi = 0; mi < 2; ++mi)
        for (int vv = 0; vv < 4; ++vv)
            bias_r[mi][vv] = bias[e * 128 + jh * 64 + wm * 32 + mi * 16 + q * 4 + vv];

    __syncthreads();                                  // sW + sF[0] ready

    #pragma unroll 1
    for (int it = 0; it < 16; ++it) {
        const int buf = it & 1;
        const __bf16* sFb = sF[buf];
        if (it < 15) {                                // prefetch next image
            const __bf16* fn = fte + (((size_t)(it + 1)) << 18);
            for (int cc = 0; cc < 4; ++cc) {
                int c = w * 4 + cc;
                int r = c * 8 + (lane >> 3);
                int g = (lane & 7) ^ (r & 7);
                gl2lds16(fn + (r << 6) + g * 8, sF[buf ^ 1] + c * 512);
            }
        }

        f32x4 acc[2][2] = {};
        #pragma unroll
        for (int tap = 0; tap < 9; ++tap) {
            const int A = tap / 3, Bt = tap - A * 3;
            const __bf16* sWt = sW + tap * 4096;
            #pragma unroll
            for (int kh = 0; kh < 2; ++kh) {
                const int kg = kh * 4;
                bf16x8 af[2], bq[2];
                #pragma unroll
                for (int mi = 0; mi < 2; ++mi) {
                    int r = wm * 32 + mi * 16 + rm;
                    int ch = (kg + q) ^ (r & 7);
                    af[mi] = *(const bf16x8*)(sWt + r * 64 + ch * 8);
                }
                #pragma unroll
                for (int ni = 0; ni < 2; ++ni) {
                    int p = wn * 32 + ni * 16 + rm;
                    int py = p >> 6, px = p & 63;
                    int xx = px + Bt; if (xx > 63) xx = 63;   // dead cols only
                    int r2 = (A + py) * 64 + xx;
                    int ch = (kg + q) ^ (r2 & 7);
                    bq[ni] = *(const bf16x8*)(sFb + r2 * 64 + ch * 8);
                }
                #pragma unroll
                for (int mi = 0; mi < 2; ++mi)
                    #pragma unroll
                    for (int ni = 0; ni < 2; ++ni)
                        acc[mi][ni] = __builtin_amdgcn_mfma_f32_16x16x32_bf16(
                            af[mi], bq[ni], acc[mi][ni], 0, 0, 0);
            }
        }

        // stores: D col(n=p)=lane&15, row(m=j)=(lane>>4)*4+reg
        const size_t eb = (size_t)(e * 32 + bg * 16 + it);
        for (int mi = 0; mi < 2; ++mi) {
            for (int ni = 0; ni < 2; ++ni) {
                int p = wn * 32 + ni * 16 + rm;
                int py = p >> 6, px = p & 63;
                if (px >= 62) continue;               // dead padding columns
                for (int vv = 0; vv < 4; ++vv) {
                    int j = jh * 64 + wm * 32 + mi * 16 + q * 4 + vv;
                    float v = acc[mi][ni][vv] + bias_r[mi][vv];
                    out[((eb * 128 + j) * 62 + (y0 + py)) * 62 + px] = v;
                }
            }
        }
        if (it < 15) __syncthreads();                 // next buf staged + safe
    }
}

extern "C" void kernel_launch(void* const* d_in, const int* in_sizes, int n_in,
                              void* d_out, int out_size, void* d_ws, size_t ws_size,
                              hipStream_t stream) {
    const float* f    = (const float*)d_in[0];
    const float* wgt  = (const float*)d_in[1];
    const float* bias = (const float*)d_in[2];
    float* out = (float*)d_out;
    __bf16* ftw = (__bf16*)d_ws;
    __bf16* wtw = (__bf16*)((char*)d_ws + FT_BYTES);

    ft_prep<<<dim3(64, 32, 4), 256, 0, stream>>>(f, ftw);
    wt_prep<<<dim3(1152), 256, 0, stream>>>(wgt, wtw);
    conv_main<<<dim3(31, 2, 8), 512, 0, stream>>>(ftw, wtw, bias, out);
}